// Round 12
// baseline (193.272 us; speedup 1.0000x reference)
//
#include <hip/hip_runtime.h>
#include <math.h>

#define BSZ 2
#define TSEQ 2048
#define CDIM 1024
#define HNUM 16

typedef __attribute__((ext_vector_type(8))) short bhalf8;
typedef __attribute__((ext_vector_type(4))) short bhalf4;
typedef __attribute__((ext_vector_type(4))) float floatx4;

__device__ __forceinline__ unsigned short f2bf(float f) {
    union { float f; unsigned u; } v;
    v.f = f;
    unsigned r = v.u + 0x7FFFu + ((v.u >> 16) & 1u);
    return (unsigned short)(r >> 16);
}

__device__ __forceinline__ floatx4 fx4_zero() { floatx4 z = {0.f,0.f,0.f,0.f}; return z; }

// async global->LDS, 16 B per lane. lds dest = (wave-uniform base) + lane*16.
typedef __attribute__((address_space(3))) unsigned int lds_u32;
typedef const __attribute__((address_space(1))) unsigned int g_u32;
__device__ __forceinline__ void async_copy16(const void* g, void* l) {
    __builtin_amdgcn_global_load_lds((g_u32*)g, (lds_u32*)l, 16, 0, 0);
}

// ---------------------------------------------------------------------------
// Merged prepass (one launch):
//  blocks [0,2048):    x fp32 -> xb bf16 (8 elems/thread)
//  blocks [2048,5120): W_attn [1024,3072] -> WtA [3072,1024] bf16 transpose
//  blocks [5120,6144): W_proj [1024,1024] -> WtP [1024,1024] bf16 transpose
// ---------------------------------------------------------------------------
__device__ __forceinline__ void trans_tile(
    const float* __restrict__ W, unsigned short* __restrict__ Wt,
    int K, int N, int n0, int k0, int tid, float (*t)[33])
{
    const int tx = tid & 31, ty = tid >> 5;
#pragma unroll
    for (int i = 0; i < 4; ++i)
        t[ty + i * 8][tx] = W[(size_t)(k0 + ty + i * 8) * N + n0 + tx];
    __syncthreads();
#pragma unroll
    for (int i = 0; i < 4; ++i)
        Wt[(size_t)(n0 + ty + i * 8) * K + k0 + tx] = f2bf(t[tx][ty + i * 8]);
}

__global__ __launch_bounds__(256) void prepass(
    const float* __restrict__ x, unsigned short* __restrict__ xb,
    const float* __restrict__ Wa, unsigned short* __restrict__ WtA,
    const float* __restrict__ Wp, unsigned short* __restrict__ WtP)
{
    __shared__ float t[32][33];
    const int bid = blockIdx.x;
    const int tid = threadIdx.x;
    if (bid < 2048) {
        size_t i = ((size_t)bid * 256 + tid) * 8;
        float4 a = *(const float4*)(x + i);
        float4 b = *(const float4*)(x + i + 4);
        uint4 o;
        o.x = (unsigned)f2bf(a.x) | ((unsigned)f2bf(a.y) << 16);
        o.y = (unsigned)f2bf(a.z) | ((unsigned)f2bf(a.w) << 16);
        o.z = (unsigned)f2bf(b.x) | ((unsigned)f2bf(b.y) << 16);
        o.w = (unsigned)f2bf(b.z) | ((unsigned)f2bf(b.w) << 16);
        *(uint4*)(xb + i) = o;
    } else if (bid < 5120) {
        int tl = bid - 2048;                       // 96 n-tiles x 32 k-tiles
        trans_tile(Wa, WtA, 1024, 3072, (tl % 96) * 32, (tl / 96) * 32, tid, t);
    } else {
        int tl = bid - 5120;                       // 32 x 32
        trans_tile(Wp, WtP, 1024, 1024, (tl % 32) * 32, (tl / 32) * 32, tid, t);
    }
}

// ---------------------------------------------------------------------------
// bf16 MFMA GEMM (B^T input) + bias, single-barrier double-buffered K-loop.
// C[M,N] = A[M,K] @ Bt[N,K]^T + bias[N].  Block tile BM x BN, K-step BK,
// 256 threads (4 waves). Wave covers (BM/2)x(BN/2); acc = MTxNT of 16x16.
// T1 XCD remap (uniform-work GEMM only; REFUTED for causal attn, r8):
// swz = (L%8)*(nwg/8) + L/8, bn-fastest chunk per XCD. nwg%8==0 holds.
// LDS swizzles (T2, both-sides: pre-swizzled GLOBAL source + swizzled read,
// LDS dest linear for global_load_lds):
//  BK=32 (row=64B): slot c = (q + (r>>1)) & 3; read sw8=((quad+(col16>>1))&3)*8
//  BK=64 (row=128B = exact bank wrap): slot c = q ^ (r&7); read chunk
//    (kk*4+quad) ^ (col16&7) -> 8-lane phase covers all 32 banks once.
// BK=64 halves the barrier count for short-K GEMMs (gemm3, r10: small win).
// gemm1 stays BK=32 (BK=64 would cut occupancy per LDS; m132 lesson).
// Blocks whose colbase >= v_start write TRANSPOSED to vt via ushort4.
// Columns < q_end get scaled by 0.125*log2(e) in fp32 before bf16 round.
// ---------------------------------------------------------------------------
template<int BM, int BN, int BK, bool OUT_BF16>
__global__ __launch_bounds__(256) void gemm_bt(
    const unsigned short* __restrict__ A, const unsigned short* __restrict__ Bt,
    const float* __restrict__ bias, void* __restrict__ Cp,
    int M, int N, int K, int v_start, unsigned short* __restrict__ vt, int q_end)
{
    constexpr int ALINES = (BM * BK) / 2048;   // 256 lanes x 8 shorts per line
    constexpr int BLINES = (BN * BK) / 2048;
    constexpr int MT = BM / 32;
    constexpr int NT = BN / 32;
    constexpr int KK = BK / 32;                 // k-chunks of 32 per step
    constexpr int CPR = BK / 8;                 // 16B-chunks per row
    __shared__ unsigned short As[2][BM * BK];
    __shared__ unsigned short Bs[2][BN * BK];

    const int tid   = threadIdx.x;
    // XCD-aware block remap (bijective: nwg % 8 == 0 for all launches)
    const int nx  = (int)gridDim.x;
    const int lin = (int)(blockIdx.y * gridDim.x + blockIdx.x);
    const int cpx = (int)(gridDim.x * gridDim.y) >> 3;
    const int swz = (lin & 7) * cpx + (lin >> 3);
    const int bn  = swz % nx;
    const int bm  = swz / nx;

    const int wave  = tid >> 6;
    const int col16 = tid & 15;
    const int quad  = (tid & 63) >> 4;
    const int wm    = (wave >> 1) * (BM / 2);
    const int wn    = (wave & 1) * (BN / 2);

    floatx4 acc[MT][NT];
#pragma unroll
    for (int i = 0; i < MT; ++i)
#pragma unroll
        for (int j = 0; j < NT; ++j) acc[i][j] = fx4_zero();

    // staging: lane covers row gr, global k-chunk pre-swizzled per BK scheme
    const int gr = tid / CPR;
    const int cq = tid % CPR;
    const int gk = (BK == 32)
        ? (((cq + 4 - ((gr >> 1) & 3)) & 3) * 8)
        : ((cq ^ (gr & 7)) * 8);
    const unsigned short* Ab = A  + (size_t)(bm * BM + gr) * K + gk;
    const unsigned short* Bb = Bt + (size_t)(bn * BN + gr) * K + gk;
    constexpr int RPL = 2048 / BK;              // rows per staged line

#define STAGE(k0, bf) { \
    char* AsB = (char*)As[bf] + wave * 1024; \
    char* BsB = (char*)Bs[bf] + wave * 1024; \
    _Pragma("unroll") \
    for (int l = 0; l < ALINES; ++l) \
        async_copy16(Ab + (size_t)l * RPL * K + (k0), AsB + l * 4096); \
    _Pragma("unroll") \
    for (int l = 0; l < BLINES; ++l) \
        async_copy16(Bb + (size_t)l * RPL * K + (k0), BsB + l * 4096); }

#define COMPUTE(bf) { \
    _Pragma("unroll") \
    for (int kk = 0; kk < KK; ++kk) { \
        const int sw8 = (BK == 32) \
            ? (((quad + (col16 >> 1)) & 3) * 8) \
            : ((((kk << 2) + quad) ^ (col16 & 7)) * 8); \
        bhalf8 a[MT], b[NT]; \
        _Pragma("unroll") \
        for (int i = 0; i < MT; ++i) \
            a[i] = *(const bhalf8*)&As[bf][(wm + i * 16 + col16) * BK + sw8]; \
        _Pragma("unroll") \
        for (int j = 0; j < NT; ++j) \
            b[j] = *(const bhalf8*)&Bs[bf][(wn + j * 16 + col16) * BK + sw8]; \
        _Pragma("unroll") \
        for (int i = 0; i < MT; ++i) \
            _Pragma("unroll") \
            for (int j = 0; j < NT; ++j) \
                acc[i][j] = __builtin_amdgcn_mfma_f32_16x16x32_bf16(a[i], b[j], acc[i][j], 0, 0, 0); \
    } }

    STAGE(0, 0);
    __syncthreads();
    int buf = 0;
    for (int k0 = 0; k0 < K - BK; k0 += BK) {
        STAGE(k0 + BK, buf ^ 1);
        COMPUTE(buf);
        __syncthreads();
        buf ^= 1;
    }
    COMPUTE(buf);
#undef STAGE
#undef COMPUTE

    const int colbase = bn * BN + wn;
    const bool vpath = (v_start >= 0) && (colbase >= v_start);  // wave-uniform
    const float csc = (colbase < q_end) ? 0.18033688f : 1.0f;   // wave-uniform
#pragma unroll
    for (int j = 0; j < NT; ++j) {
        int col = colbase + j * 16 + col16;
        float bv = bias[col];
#pragma unroll
        for (int i = 0; i < MT; ++i) {
            if (vpath) {
                int row0 = bm * BM + wm + i * 16 + quad * 4;
                ushort4 o;
                o.x = f2bf((acc[i][j][0] + bv) * csc);
                o.y = f2bf((acc[i][j][1] + bv) * csc);
                o.z = f2bf((acc[i][j][2] + bv) * csc);
                o.w = f2bf((acc[i][j][3] + bv) * csc);
                size_t vrow = (size_t)((row0 >> 11) * 1024 + (col - v_start));
                *(ushort4*)(vt + vrow * 2048 + (row0 & 2047)) = o;
            } else {
#pragma unroll
                for (int r = 0; r < 4; ++r) {
                    int row = bm * BM + wm + i * 16 + quad * 4 + r;
                    float v = (acc[i][j][r] + bv) * csc;
                    if (OUT_BF16)
                        ((unsigned short*)Cp)[(size_t)row * N + col] = f2bf(v);
                    else
                        ((float*)Cp)[(size_t)row * N + col] = v;
                }
            }
        }
    }
}

// ---------------------------------------------------------------------------
// MFMA flash attention v9: QBLK=128, 4 waves x 32 q-rows (256 thr).
// r11 diagnosis: v6b is LDS-read-BW bound -- 4 waves each read 16 KB of
// K/V fragments per tile (4x redundancy on a shared 17.5 KB tile), ~82 KB
// LDS traffic per tile-event x 528 events/(b,h).  v9 gives each wave TWO
// Q fragments (qA: block rows [0,64), qB: [64,128)) and reuses every
// k0/k1/av LDS read for both -> per-(b,h) tile-events 528 -> 272 with the
// same per-event cost: LDS read + staging traffic per q HALVED.
// (r6/r7's 8-wave QBLK=128 kept the redundancy ratio -- that's why it was
// null; this is the 4-wave variant that actually cuts traffic.)
// Causality (wave-uniform): kb<2Q full/full; kb==2Q diagA/fullB;
// kb==2Q+1 skipA/diagB.  Grid 32x16, 2 blocks/CU; per-CU load balanced by
// Q = (y<8)? 15-y : y-8  (each CU hosts Q and 15-Q -> 36 tile-events).
// Layouts FROZEN from v6b (single-variable rule): K row*128B +
// (chunk^(row&7))*16B async-staged; V stride-76 reg-staged; same maps.
// REFUTED levers: split-acc+setprio (r4); 8-wave QBLK=128 (r6/r7);
// XCD head-chunk (r8); per-CU qb-sum balance at QBLK=64 (r11, null).
// ---------------------------------------------------------------------------
template<int MODE>   // 0: full/full  1: diagA/fullB  2: skipA/diagB
__device__ __forceinline__ void attn_tile2(
    const unsigned short* __restrict__ Ks, const unsigned short* __restrict__ Vt,
    const bhalf8* qfA, const bhalf8* qfB,
    floatx4* oTA, floatx4* oTB, floatx4& acclA, floatx4& acclB,
    int col16, int quad, int qloc)
{
    const int sx = col16 & 7;
    const floatx4 minusC = {-17.31234049f, -17.31234049f, -17.31234049f, -17.31234049f};
    const bhalf4 ones = {0x3F80, 0x3F80, 0x3F80, 0x3F80};   // bf16 1.0 x4

    floatx4 sA[4], sB[4];
#pragma unroll
    for (int n = 0; n < 4; ++n) {
        const int row = 16 * n + col16;
        bhalf8 k0 = *(const bhalf8*)&Ks[row * 64 + ((quad ^ sx) * 8)];
        bhalf8 k1 = *(const bhalf8*)&Ks[row * 64 + (((4 + quad) ^ sx) * 8)];
        if (MODE != 2) {
            floatx4 t = __builtin_amdgcn_mfma_f32_16x16x32_bf16(k0, qfA[0], minusC, 0, 0, 0);
            sA[n] = __builtin_amdgcn_mfma_f32_16x16x32_bf16(k1, qfA[1], t, 0, 0, 0);
        }
        floatx4 u = __builtin_amdgcn_mfma_f32_16x16x32_bf16(k0, qfB[0], minusC, 0, 0, 0);
        sB[n] = __builtin_amdgcn_mfma_f32_16x16x32_bf16(k1, qfB[1], u, 0, 0, 0);
    }

    bhalf4 pbA[4], pbB[4];
#pragma unroll
    for (int n = 0; n < 4; ++n) {
        if (MODE != 2) {
            unsigned a[4];
#pragma unroll
            for (int r = 0; r < 4; ++r) {
                float p = exp2f(sA[n][r]);
                if (MODE == 1) { if (16 * n + quad * 4 + r > qloc) p = 0.f; }
                a[r] = __float_as_uint(p) + 0x8000u;   // bias-round to bf16
            }
            union { unsigned u[2]; bhalf4 b; } ua;
            ua.u[0] = (a[0] >> 16) | (a[1] & 0xffff0000u);
            ua.u[1] = (a[2] >> 16) | (a[3] & 0xffff0000u);
            pbA[n] = ua.b;
            acclA = __builtin_amdgcn_mfma_f32_16x16x16bf16_1k(ones, pbA[n], acclA, 0, 0, 0);
        }
        unsigned c[4];
#pragma unroll
        for (int r = 0; r < 4; ++r) {
            float p = exp2f(sB[n][r]);
            if (MODE == 2) { if (16 * n + quad * 4 + r > qloc) p = 0.f; }
            c[r] = __float_as_uint(p) + 0x8000u;
        }
        union { unsigned u[2]; bhalf4 b; } ub;
        ub.u[0] = (c[0] >> 16) | (c[1] & 0xffff0000u);
        ub.u[1] = (c[2] >> 16) | (c[3] & 0xffff0000u);
        pbB[n] = ub.b;
        acclB = __builtin_amdgcn_mfma_f32_16x16x16bf16_1k(ones, pbB[n], acclB, 0, 0, 0);
    }

#pragma unroll
    for (int n = 0; n < 4; ++n) {
#pragma unroll
        for (int dt = 0; dt < 4; ++dt) {
            const int d = 16 * dt + col16;
            const bhalf4 av = *(const bhalf4*)&Vt[d * 76 + 16 * n + quad * 4];
            if (MODE != 2)
                oTA[dt] = __builtin_amdgcn_mfma_f32_16x16x16bf16_1k(av, pbA[n], oTA[dt], 0, 0, 0);
            oTB[dt] = __builtin_amdgcn_mfma_f32_16x16x16bf16_1k(av, pbB[n], oTB[dt], 0, 0, 0);
        }
    }
}

__global__ __launch_bounds__(256) void attn_mfma(
    const unsigned short* __restrict__ qkv,
    const unsigned short* __restrict__ vT,
    unsigned short* __restrict__ yout)
{
    __shared__ unsigned short Kbuf[2][64 * 64];
    __shared__ unsigned short Vbuf[2][64 * 76];

    const int tid   = threadIdx.x;
    const int wave  = tid >> 6;
    const int col16 = tid & 15;
    const int quad  = (tid & 63) >> 4;

    // balanced Q pairing: each CU hosts {Q, 15-Q} -> constant 36 tiles/CU
    const int y = (int)blockIdx.y;               // 0..15
    const int Q = (y < 8) ? 15 - y : y - 8;

    const int bh = blockIdx.x;
    const int b  = bh >> 4;
    const int h  = bh & 15;

    const unsigned short* base  = qkv + (size_t)b * TSEQ * 3072 + h * 64;
    const unsigned short* kbase = base + CDIM;
    const unsigned short* vtb   = vT + (size_t)(b * 1024 + h * 64) * 2048;

    // Q fragments: qA = block rows [0,64), qB = [64,128)
    bhalf8 qfA[2], qfB[2];
    {
        const unsigned short* qrowA =
            base + (size_t)(Q * 128 + wave * 16 + col16) * 3072 + quad * 8;
        qfA[0] = *(const bhalf8*)qrowA;
        qfA[1] = *(const bhalf8*)(qrowA + 32);
        const unsigned short* qrowB = qrowA + (size_t)64 * 3072;
        qfB[0] = *(const bhalf8*)qrowB;
        qfB[1] = *(const bhalf8*)(qrowB + 32);
    }

    // K staging map: lane covers K row (tid>>3)(+32), chunk (tid&7)^(row&7)
    const int krow = tid >> 3;
    const int kchk = (tid & 7) ^ (krow & 7);
    const unsigned short* ksrc0 = kbase + (size_t)krow * 3072 + kchk * 8;
    const unsigned short* ksrc1 = kbase + (size_t)(krow + 32) * 3072 + kchk * 8;

    // V staging map: lane covers vT row d=(tid>>3)(+32), t chunk (tid&7)*8
    const int vd  = tid >> 3;
    const int vt0 = (tid & 7) * 8;
    const unsigned short* vsrc0 = vtb + (size_t)vd * 2048 + vt0;
    const unsigned short* vsrc1 = vtb + (size_t)(vd + 32) * 2048 + vt0;

#define KSTAGE(kb, bf) { \
    char* Kd = (char*)Kbuf[bf] + wave * 1024; \
    async_copy16(ksrc0 + (size_t)(kb) * 64 * 3072, Kd); \
    async_copy16(ksrc1 + (size_t)(kb) * 64 * 3072, Kd + 4096); }

    floatx4 oTA[4], oTB[4];
#pragma unroll
    for (int dt = 0; dt < 4; ++dt) { oTA[dt] = fx4_zero(); oTB[dt] = fx4_zero(); }
    floatx4 acclA = fx4_zero(), acclB = fx4_zero();
    const int qloc = wave * 16 + col16;

    {   // prologue: stage tile 0 into buf 0
        uint4 nv0 = *(const uint4*)vsrc0;
        uint4 nv1 = *(const uint4*)vsrc1;
        KSTAGE(0, 0);
        *(uint4*)&Vbuf[0][vd * 76 + vt0]        = nv0;
        *(uint4*)&Vbuf[0][(vd + 32) * 76 + vt0] = nv1;
    }
    __syncthreads();
    int buf = 0;
    const int kd = 2 * Q;                 // diag-A tile index; last tile = kd+1
    for (int kb = 0; kb < kd; ++kb) {
        uint4 nv0 = *(const uint4*)(vsrc0 + (size_t)(kb + 1) * 64);
        uint4 nv1 = *(const uint4*)(vsrc1 + (size_t)(kb + 1) * 64);
        KSTAGE(kb + 1, buf ^ 1);
        attn_tile2<0>(Kbuf[buf], Vbuf[buf], qfA, qfB, oTA, oTB, acclA, acclB,
                      col16, quad, qloc);
        *(uint4*)&Vbuf[buf ^ 1][vd * 76 + vt0]        = nv0;
        *(uint4*)&Vbuf[buf ^ 1][(vd + 32) * 76 + vt0] = nv1;
        __syncthreads();
        buf ^= 1;
    }
    {   // tile kd: diag for qA, full for qB; stage tile kd+1
        uint4 nv0 = *(const uint4*)(vsrc0 + (size_t)(kd + 1) * 64);
        uint4 nv1 = *(const uint4*)(vsrc1 + (size_t)(kd + 1) * 64);
        KSTAGE(kd + 1, buf ^ 1);
        attn_tile2<1>(Kbuf[buf], Vbuf[buf], qfA, qfB, oTA, oTB, acclA, acclB,
                      col16, quad, qloc);
        *(uint4*)&Vbuf[buf ^ 1][vd * 76 + vt0]        = nv0;
        *(uint4*)&Vbuf[buf ^ 1][(vd + 32) * 76 + vt0] = nv1;
        __syncthreads();
        buf ^= 1;
    }
    // final tile kd+1: qA fully masked (skipped), diag for qB
    attn_tile2<2>(Kbuf[buf], Vbuf[buf], qfA, qfB, oTA, oTB, acclA, acclB,
                  col16, quad, qloc);
#undef KSTAGE

    // epilogue: every lane holds full l for its two q-rows; O^T/l, store
    const float invA = 1.0f / acclA[0];
    const float invB = 1.0f / acclB[0];
    const size_t rowA = (size_t)b * TSEQ + (size_t)Q * 128 + wave * 16 + col16;
    const size_t rowB = rowA + 64;
#pragma unroll
    for (int dt = 0; dt < 4; ++dt) {
        ushort4 oA, oB;
        oA.x = f2bf(oTA[dt][0] * invA);
        oA.y = f2bf(oTA[dt][1] * invA);
        oA.z = f2bf(oTA[dt][2] * invA);
        oA.w = f2bf(oTA[dt][3] * invA);
        oB.x = f2bf(oTB[dt][0] * invB);
        oB.y = f2bf(oTB[dt][1] * invB);
        oB.z = f2bf(oTB[dt][2] * invB);
        oB.w = f2bf(oTB[dt][3] * invB);
        *(ushort4*)(yout + rowA * CDIM + h * 64 + 16 * dt + quad * 4) = oA;
        *(ushort4*)(yout + rowB * CDIM + h * 64 + 16 * dt + quad * 4) = oB;
    }
}

// ---------------------------------------------------------------------------
extern "C" void kernel_launch(void* const* d_in, const int* in_sizes, int n_in,
                              void* d_out, int out_size, void* d_ws, size_t ws_size,
                              hipStream_t stream)
{
    const float* x      = (const float*)d_in[0];   // [2,2048,1024]
    const float* W_attn = (const float*)d_in[1];   // [1024,3072]
    const float* b_attn = (const float*)d_in[2];   // [3072]
    const float* W_proj = (const float*)d_in[3];   // [1024,1024]
    const float* b_proj = (const float*)d_in[4];   // [1024]
    float* out = (float*)d_out;                    // [2,2048,1024] fp32

    unsigned short* qkv = (unsigned short*)d_ws;             // bf16 [4096,3072] (V third unused)
    unsigned short* y   = qkv + (size_t)4096 * 3072;         // bf16 [4096,1024]
    unsigned short* xb  = y   + (size_t)4096 * 1024;         // bf16 [4096,1024]
    unsigned short* WtA = xb  + (size_t)4096 * 1024;         // bf16 [3072,1024]
    unsigned short* WtP = WtA + (size_t)3072 * 1024;         // bf16 [1024,1024]
    unsigned short* vT  = WtP + (size_t)1024 * 1024;         // bf16 [2048,2048]

    // 0) merged prepass: x->bf16, both weight transposes (one launch)
    prepass<<<dim3(6144), 256, 0, stream>>>(x, xb, W_attn, WtA, W_proj, WtP);

    // 1) qkv = bf16(x @ W_attn + b_attn); Q cols pre-scaled by 0.125*log2e;
    //    V cols (>=2048) transposed to vT.  BK=32
    gemm_bt<128, 128, 32, true><<<dim3(3072 / 128, 4096 / 128), 256, 0, stream>>>(
        xb, WtA, b_attn, qkv, 4096, 3072, 1024, 2048, vT, 1024);

    // 2) flash attention -> y bf16 [4096,1024]
    //    v9: QBLK=128, 4 waves x 32 q-rows, grid 32x16 (2 blocks/CU)
    attn_mfma<<<dim3(BSZ * HNUM, TSEQ / 128), 256, 0, stream>>>(qkv, vT, y);

    // 3) out = y @ W_proj + b_proj (fp32)  M=4096 N=1024 K=1024.
    //    BK=64: 16 K-steps, 16 MFMA/wave/step, XOR-swizzled LDS
    gemm_bt<64, 128, 64, false><<<dim3(1024 / 128, 4096 / 64), 256, 0, stream>>>(
        y, WtP, b_proj, out, 4096, 1024, 1024, -1, nullptr, 0);
}

// Round 14
// 175.654 us; speedup vs baseline: 1.1003x; 1.1003x over previous
//
#include <hip/hip_runtime.h>
#include <math.h>

#define BSZ 2
#define TSEQ 2048
#define CDIM 1024
#define HNUM 16

typedef __attribute__((ext_vector_type(8))) short bhalf8;
typedef __attribute__((ext_vector_type(4))) short bhalf4;
typedef __attribute__((ext_vector_type(4))) float floatx4;

__device__ __forceinline__ unsigned short f2bf(float f) {
    union { float f; unsigned u; } v;
    v.f = f;
    unsigned r = v.u + 0x7FFFu + ((v.u >> 16) & 1u);
    return (unsigned short)(r >> 16);
}

__device__ __forceinline__ floatx4 fx4_zero() { floatx4 z = {0.f,0.f,0.f,0.f}; return z; }

// async global->LDS, 16 B per lane. lds dest = (wave-uniform base) + lane*16.
typedef __attribute__((address_space(3))) unsigned int lds_u32;
typedef const __attribute__((address_space(1))) unsigned int g_u32;
__device__ __forceinline__ void async_copy16(const void* g, void* l) {
    __builtin_amdgcn_global_load_lds((g_u32*)g, (lds_u32*)l, 16, 0, 0);
}

// ---------------------------------------------------------------------------
// Merged prepass (one launch):
//  blocks [0,2048):    x fp32 -> xb bf16 (8 elems/thread)
//  blocks [2048,5120): W_attn [1024,3072] -> WtA [3072,1024] bf16 transpose
//  blocks [5120,6144): W_proj [1024,1024] -> WtP [1024,1024] bf16 transpose
// ---------------------------------------------------------------------------
__device__ __forceinline__ void trans_tile(
    const float* __restrict__ W, unsigned short* __restrict__ Wt,
    int K, int N, int n0, int k0, int tid, float (*t)[33])
{
    const int tx = tid & 31, ty = tid >> 5;
#pragma unroll
    for (int i = 0; i < 4; ++i)
        t[ty + i * 8][tx] = W[(size_t)(k0 + ty + i * 8) * N + n0 + tx];
    __syncthreads();
#pragma unroll
    for (int i = 0; i < 4; ++i)
        Wt[(size_t)(n0 + ty + i * 8) * K + k0 + tx] = f2bf(t[tx][ty + i * 8]);
}

__global__ __launch_bounds__(256) void prepass(
    const float* __restrict__ x, unsigned short* __restrict__ xb,
    const float* __restrict__ Wa, unsigned short* __restrict__ WtA,
    const float* __restrict__ Wp, unsigned short* __restrict__ WtP)
{
    __shared__ float t[32][33];
    const int bid = blockIdx.x;
    const int tid = threadIdx.x;
    if (bid < 2048) {
        size_t i = ((size_t)bid * 256 + tid) * 8;
        float4 a = *(const float4*)(x + i);
        float4 b = *(const float4*)(x + i + 4);
        uint4 o;
        o.x = (unsigned)f2bf(a.x) | ((unsigned)f2bf(a.y) << 16);
        o.y = (unsigned)f2bf(a.z) | ((unsigned)f2bf(a.w) << 16);
        o.z = (unsigned)f2bf(b.x) | ((unsigned)f2bf(b.y) << 16);
        o.w = (unsigned)f2bf(b.z) | ((unsigned)f2bf(b.w) << 16);
        *(uint4*)(xb + i) = o;
    } else if (bid < 5120) {
        int tl = bid - 2048;                       // 96 n-tiles x 32 k-tiles
        trans_tile(Wa, WtA, 1024, 3072, (tl % 96) * 32, (tl / 96) * 32, tid, t);
    } else {
        int tl = bid - 5120;                       // 32 x 32
        trans_tile(Wp, WtP, 1024, 1024, (tl % 32) * 32, (tl / 32) * 32, tid, t);
    }
}

// ---------------------------------------------------------------------------
// bf16 MFMA GEMM (B^T input) + bias, single-barrier double-buffered K-loop.
// C[M,N] = A[M,K] @ Bt[N,K]^T + bias[N].  Block tile BM x BN, K-step BK,
// 256 threads (4 waves). Wave covers (BM/2)x(BN/2); acc = MTxNT of 16x16.
// T1 XCD remap (uniform-work GEMM only; REFUTED for causal attn, r8):
// swz = (L%8)*(nwg/8) + L/8, bn-fastest chunk per XCD. nwg%8==0 holds.
// LDS swizzles (T2, both-sides: pre-swizzled GLOBAL source + swizzled read,
// LDS dest linear for global_load_lds):
//  BK=32 (row=64B): slot c = (q + (r>>1)) & 3; read sw8=((quad+(col16>>1))&3)*8
//  BK=64 (row=128B = exact bank wrap): slot c = q ^ (r&7); read chunk
//    (kk*4+quad) ^ (col16&7) -> 8-lane phase covers all 32 banks once.
// BK=64 halves the barrier count for short-K GEMMs (gemm3, r10: small win).
// gemm1 stays BK=32 (BK=64 would cut occupancy per LDS; m132 lesson).
// Blocks whose colbase >= v_start write TRANSPOSED to vt via ushort4.
// Columns < q_end get scaled by 0.125*log2(e) in fp32 before bf16 round.
// ---------------------------------------------------------------------------
template<int BM, int BN, int BK, bool OUT_BF16>
__global__ __launch_bounds__(256) void gemm_bt(
    const unsigned short* __restrict__ A, const unsigned short* __restrict__ Bt,
    const float* __restrict__ bias, void* __restrict__ Cp,
    int M, int N, int K, int v_start, unsigned short* __restrict__ vt, int q_end)
{
    constexpr int ALINES = (BM * BK) / 2048;   // 256 lanes x 8 shorts per line
    constexpr int BLINES = (BN * BK) / 2048;
    constexpr int MT = BM / 32;
    constexpr int NT = BN / 32;
    constexpr int KK = BK / 32;                 // k-chunks of 32 per step
    constexpr int CPR = BK / 8;                 // 16B-chunks per row
    __shared__ unsigned short As[2][BM * BK];
    __shared__ unsigned short Bs[2][BN * BK];

    const int tid   = threadIdx.x;
    // XCD-aware block remap (bijective: nwg % 8 == 0 for all launches)
    const int nx  = (int)gridDim.x;
    const int lin = (int)(blockIdx.y * gridDim.x + blockIdx.x);
    const int cpx = (int)(gridDim.x * gridDim.y) >> 3;
    const int swz = (lin & 7) * cpx + (lin >> 3);
    const int bn  = swz % nx;
    const int bm  = swz / nx;

    const int wave  = tid >> 6;
    const int col16 = tid & 15;
    const int quad  = (tid & 63) >> 4;
    const int wm    = (wave >> 1) * (BM / 2);
    const int wn    = (wave & 1) * (BN / 2);

    floatx4 acc[MT][NT];
#pragma unroll
    for (int i = 0; i < MT; ++i)
#pragma unroll
        for (int j = 0; j < NT; ++j) acc[i][j] = fx4_zero();

    // staging: lane covers row gr, global k-chunk pre-swizzled per BK scheme
    const int gr = tid / CPR;
    const int cq = tid % CPR;
    const int gk = (BK == 32)
        ? (((cq + 4 - ((gr >> 1) & 3)) & 3) * 8)
        : ((cq ^ (gr & 7)) * 8);
    const unsigned short* Ab = A  + (size_t)(bm * BM + gr) * K + gk;
    const unsigned short* Bb = Bt + (size_t)(bn * BN + gr) * K + gk;
    constexpr int RPL = 2048 / BK;              // rows per staged line

#define STAGE(k0, bf) { \
    char* AsB = (char*)As[bf] + wave * 1024; \
    char* BsB = (char*)Bs[bf] + wave * 1024; \
    _Pragma("unroll") \
    for (int l = 0; l < ALINES; ++l) \
        async_copy16(Ab + (size_t)l * RPL * K + (k0), AsB + l * 4096); \
    _Pragma("unroll") \
    for (int l = 0; l < BLINES; ++l) \
        async_copy16(Bb + (size_t)l * RPL * K + (k0), BsB + l * 4096); }

#define COMPUTE(bf) { \
    _Pragma("unroll") \
    for (int kk = 0; kk < KK; ++kk) { \
        const int sw8 = (BK == 32) \
            ? (((quad + (col16 >> 1)) & 3) * 8) \
            : ((((kk << 2) + quad) ^ (col16 & 7)) * 8); \
        bhalf8 a[MT], b[NT]; \
        _Pragma("unroll") \
        for (int i = 0; i < MT; ++i) \
            a[i] = *(const bhalf8*)&As[bf][(wm + i * 16 + col16) * BK + sw8]; \
        _Pragma("unroll") \
        for (int j = 0; j < NT; ++j) \
            b[j] = *(const bhalf8*)&Bs[bf][(wn + j * 16 + col16) * BK + sw8]; \
        _Pragma("unroll") \
        for (int i = 0; i < MT; ++i) \
            _Pragma("unroll") \
            for (int j = 0; j < NT; ++j) \
                acc[i][j] = __builtin_amdgcn_mfma_f32_16x16x32_bf16(a[i], b[j], acc[i][j], 0, 0, 0); \
    } }

    STAGE(0, 0);
    __syncthreads();
    int buf = 0;
    for (int k0 = 0; k0 < K - BK; k0 += BK) {
        STAGE(k0 + BK, buf ^ 1);
        COMPUTE(buf);
        __syncthreads();
        buf ^= 1;
    }
    COMPUTE(buf);
#undef STAGE
#undef COMPUTE

    const int colbase = bn * BN + wn;
    const bool vpath = (v_start >= 0) && (colbase >= v_start);  // wave-uniform
    const float csc = (colbase < q_end) ? 0.18033688f : 1.0f;   // wave-uniform
#pragma unroll
    for (int j = 0; j < NT; ++j) {
        int col = colbase + j * 16 + col16;
        float bv = bias[col];
#pragma unroll
        for (int i = 0; i < MT; ++i) {
            if (vpath) {
                int row0 = bm * BM + wm + i * 16 + quad * 4;
                ushort4 o;
                o.x = f2bf((acc[i][j][0] + bv) * csc);
                o.y = f2bf((acc[i][j][1] + bv) * csc);
                o.z = f2bf((acc[i][j][2] + bv) * csc);
                o.w = f2bf((acc[i][j][3] + bv) * csc);
                size_t vrow = (size_t)((row0 >> 11) * 1024 + (col - v_start));
                *(ushort4*)(vt + vrow * 2048 + (row0 & 2047)) = o;
            } else {
#pragma unroll
                for (int r = 0; r < 4; ++r) {
                    int row = bm * BM + wm + i * 16 + quad * 4 + r;
                    float v = (acc[i][j][r] + bv) * csc;
                    if (OUT_BF16)
                        ((unsigned short*)Cp)[(size_t)row * N + col] = f2bf(v);
                    else
                        ((float*)Cp)[(size_t)row * N + col] = v;
                }
            }
        }
    }
}

// ---------------------------------------------------------------------------
// MFMA flash attention v6d (r11 session-best config): v6b datapath + balanced
// qb permutation.  S^T = K.Q^T (16x16x32); O^T = V^T.P^T (16x16x16, P^T from
// regs).  Q pre-scaled by 0.125*log2e (folded into GEMM-1); -17.312 shift
// folded into QK^T accumulator init; softmax inner loop = exp2 + bit-pack;
// l accumulated on the MFMA pipe as ones^T.P^T (no epilogue shuffle).
// SESSION CONCLUSION (r12): the 45-48 us plateau is latency-bound and hidden
// by cross-block TLP -- 4 independent co-resident blocks/CU (LDS-capped max)
// overlap each other's barrier+vmcnt drains.  Every incremental structural
// lever is resolved-negative: split-acc+setprio (r4, +4us); 8-wave QBLK=128
// (r6/r7, +6..11us); XCD head-chunk (r8, +30us); per-CU qb-balance (r11,
// null); 4-wave QBLK=128 2-LDS-reuse (r12, +13us -- halved occupancy 16->8
// waves/CU outweighed halved LDS traffic).  Past this: ground-up 8-phase
// counted-vmcnt pipeline rewrite (HK-style), not an incremental edit.
// K image:  row*128B + (chunk ^ (row&7))*16B (async-staged; conflict-free).
// V image: Vt[d*76 + t]; PV b64 read bank start 6*col16 -> conflict-free.
// ---------------------------------------------------------------------------
template<bool DIAG>
__device__ __forceinline__ void attn_tile(
    const unsigned short* __restrict__ Ks, const unsigned short* __restrict__ Vt,
    const bhalf8* qf, floatx4* oT, floatx4& accl,
    int col16, int quad, int qloc)
{
    const int sx = col16 & 7;
    const floatx4 minusC = {-17.31234049f, -17.31234049f, -17.31234049f, -17.31234049f};
    const bhalf4 ones = {0x3F80, 0x3F80, 0x3F80, 0x3F80};   // bf16 1.0 x4

    floatx4 s[4];
#pragma unroll
    for (int n = 0; n < 4; ++n) {
        const int row = 16 * n + col16;
        bhalf8 k0 = *(const bhalf8*)&Ks[row * 64 + ((quad ^ sx) * 8)];
        bhalf8 k1 = *(const bhalf8*)&Ks[row * 64 + (((4 + quad) ^ sx) * 8)];
        floatx4 t = __builtin_amdgcn_mfma_f32_16x16x32_bf16(k0, qf[0], minusC, 0, 0, 0);
        s[n] = __builtin_amdgcn_mfma_f32_16x16x32_bf16(k1, qf[1], t, 0, 0, 0);
    }

    bhalf4 pb[4];
#pragma unroll
    for (int n = 0; n < 4; ++n) {
        unsigned a[4];
#pragma unroll
        for (int r = 0; r < 4; ++r) {
            float p = exp2f(s[n][r]);
            if (DIAG) {
                if (16 * n + quad * 4 + r > qloc) p = 0.f;
            }
            a[r] = __float_as_uint(p) + 0x8000u;   // bias-round to bf16
        }
        union { unsigned u[2]; bhalf4 b; } uu;
        uu.u[0] = (a[0] >> 16) | (a[1] & 0xffff0000u);
        uu.u[1] = (a[2] >> 16) | (a[3] & 0xffff0000u);
        pb[n] = uu.b;
        // l-partial on the MFMA pipe: C[*][q] += sum_k P^T[k][q]
        accl = __builtin_amdgcn_mfma_f32_16x16x16bf16_1k(ones, pb[n], accl, 0, 0, 0);
    }

#pragma unroll
    for (int n = 0; n < 4; ++n) {
#pragma unroll
        for (int dt = 0; dt < 4; ++dt) {
            const int d = 16 * dt + col16;
            const bhalf4 av = *(const bhalf4*)&Vt[d * 76 + 16 * n + quad * 4];
            oT[dt] = __builtin_amdgcn_mfma_f32_16x16x16bf16_1k(av, pb[n], oT[dt], 0, 0, 0);
        }
    }
}

__global__ __launch_bounds__(256) void attn_mfma(
    const unsigned short* __restrict__ qkv,
    const unsigned short* __restrict__ vT,
    unsigned short* __restrict__ yout)
{
    __shared__ unsigned short Kbuf[2][64 * 64];
    __shared__ unsigned short Vbuf[2][64 * 76];

    const int tid   = threadIdx.x;
    const int wave  = tid >> 6;
    const int col16 = tid & 15;
    const int quad  = (tid & 63) >> 4;

    // balanced qb permutation (constant per-CU load)
    const int y = (int)blockIdx.y;
    const int g = y >> 3, r = y & 7;
    const int qb = (g == 0) ? 31 - r : (g == 1) ? r : (g == 2) ? 23 - r : 8 + r;

    const int bh    = blockIdx.x;
    const int b     = bh >> 4;
    const int h     = bh & 15;

    const unsigned short* base  = qkv + (size_t)b * TSEQ * 3072 + h * 64;
    const unsigned short* kbase = base + CDIM;
    const unsigned short* vtb   = vT + (size_t)(b * 1024 + h * 64) * 2048;

    // Q fragments (B-layout for S^T): lane holds Q[q=wave*16+col16][d=quad*8+j]
    bhalf8 qf[2];
    {
        const unsigned short* qrow =
            base + (size_t)(qb * 64 + wave * 16 + col16) * 3072 + quad * 8;
        qf[0] = *(const bhalf8*)qrow;
        qf[1] = *(const bhalf8*)(qrow + 32);
    }

    // K staging map: lane covers K row (tid>>3)(+32), chunk (tid&7)^(row&7)
    const int krow = tid >> 3;
    const int kchk = (tid & 7) ^ (krow & 7);
    const unsigned short* ksrc0 = kbase + (size_t)krow * 3072 + kchk * 8;
    const unsigned short* ksrc1 = kbase + (size_t)(krow + 32) * 3072 + kchk * 8;

    // V staging map: lane covers vT row d=(tid>>3)(+32), t chunk (tid&7)*8
    const int vd  = tid >> 3;
    const int vt0 = (tid & 7) * 8;
    const unsigned short* vsrc0 = vtb + (size_t)vd * 2048 + vt0;
    const unsigned short* vsrc1 = vtb + (size_t)(vd + 32) * 2048 + vt0;

#define KSTAGE(kb, bf) { \
    char* Kd = (char*)Kbuf[bf] + wave * 1024; \
    async_copy16(ksrc0 + (size_t)(kb) * 64 * 3072, Kd); \
    async_copy16(ksrc1 + (size_t)(kb) * 64 * 3072, Kd + 4096); }

    floatx4 oT[4];
#pragma unroll
    for (int dt = 0; dt < 4; ++dt) oT[dt] = fx4_zero();
    floatx4 accl = fx4_zero();
    const int qloc = wave * 16 + col16;

    {   // prologue: stage tile 0 into buf 0
        uint4 nv0 = *(const uint4*)vsrc0;
        uint4 nv1 = *(const uint4*)vsrc1;
        KSTAGE(0, 0);
        *(uint4*)&Vbuf[0][vd * 76 + vt0]        = nv0;
        *(uint4*)&Vbuf[0][(vd + 32) * 76 + vt0] = nv1;
    }
    __syncthreads();
    int buf = 0;
    for (int kb = 0; kb < qb; ++kb) {
        uint4 nv0 = *(const uint4*)(vsrc0 + (size_t)(kb + 1) * 64);
        uint4 nv1 = *(const uint4*)(vsrc1 + (size_t)(kb + 1) * 64);
        KSTAGE(kb + 1, buf ^ 1);
        attn_tile<false>(Kbuf[buf], Vbuf[buf], qf, oT, accl, col16, quad, qloc);
        *(uint4*)&Vbuf[buf ^ 1][vd * 76 + vt0]        = nv0;
        *(uint4*)&Vbuf[buf ^ 1][(vd + 32) * 76 + vt0] = nv1;
        __syncthreads();
        buf ^= 1;
    }
    attn_tile<true>(Kbuf[buf], Vbuf[buf], qf, oT, accl, col16, quad, qloc);
#undef KSTAGE

    // epilogue: every lane already holds the full l for its q; O^T/l, store
    const float inv = 1.0f / accl[0];
    const size_t row = (size_t)b * TSEQ + (size_t)qb * 64 + wave * 16 + col16;
#pragma unroll
    for (int dt = 0; dt < 4; ++dt) {
        ushort4 o;
        o.x = f2bf(oT[dt][0] * inv);
        o.y = f2bf(oT[dt][1] * inv);
        o.z = f2bf(oT[dt][2] * inv);
        o.w = f2bf(oT[dt][3] * inv);
        *(ushort4*)(yout + row * CDIM + h * 64 + 16 * dt + quad * 4) = o;
    }
}

// ---------------------------------------------------------------------------
extern "C" void kernel_launch(void* const* d_in, const int* in_sizes, int n_in,
                              void* d_out, int out_size, void* d_ws, size_t ws_size,
                              hipStream_t stream)
{
    const float* x      = (const float*)d_in[0];   // [2,2048,1024]
    const float* W_attn = (const float*)d_in[1];   // [1024,3072]
    const float* b_attn = (const float*)d_in[2];   // [3072]
    const float* W_proj = (const float*)d_in[3];   // [1024,1024]
    const float* b_proj = (const float*)d_in[4];   // [1024]
    float* out = (float*)d_out;                    // [2,2048,1024] fp32

    unsigned short* qkv = (unsigned short*)d_ws;             // bf16 [4096,3072] (V third unused)
    unsigned short* y   = qkv + (size_t)4096 * 3072;         // bf16 [4096,1024]
    unsigned short* xb  = y   + (size_t)4096 * 1024;         // bf16 [4096,1024]
    unsigned short* WtA = xb  + (size_t)4096 * 1024;         // bf16 [3072,1024]
    unsigned short* WtP = WtA + (size_t)3072 * 1024;         // bf16 [1024,1024]
    unsigned short* vT  = WtP + (size_t)1024 * 1024;         // bf16 [2048,2048]

    // 0) merged prepass: x->bf16, both weight transposes (one launch)
    prepass<<<dim3(6144), 256, 0, stream>>>(x, xb, W_attn, WtA, W_proj, WtP);

    // 1) qkv = bf16(x @ W_attn + b_attn); Q cols pre-scaled by 0.125*log2e;
    //    V cols (>=2048) transposed to vT.  BK=32
    gemm_bt<128, 128, 32, true><<<dim3(3072 / 128, 4096 / 128), 256, 0, stream>>>(
        xb, WtA, b_attn, qkv, 4096, 3072, 1024, 2048, vT, 1024);

    // 2) flash attention -> y bf16 [4096,1024]  (v6d: balanced qb permutation)
    attn_mfma<<<dim3(BSZ * HNUM, TSEQ / 64), 256, 0, stream>>>(qkv, vT, y);

    // 3) out = y @ W_proj + b_proj (fp32)  M=4096 N=1024 K=1024.
    //    BK=64: 16 K-steps, 16 MFMA/wave/step, XOR-swizzled LDS
    gemm_bt<64, 128, 64, false><<<dim3(1024 / 128, 4096 / 64), 256, 0, stream>>>(
        y, WtP, b_proj, out, 4096, 1024, 1024, -1, nullptr, 0);
}